// Round 5
// baseline (1824.168 us; speedup 1.0000x reference)
//
#include <hip/hip_runtime.h>
#include <hip/hip_bf16.h>

#define TSTEP 14
#define BROWS 64          // batch rows per block (8 waves: full 128-col coverage)
#define KCOMB 160         // 128 (h) + 16 (emb) + 16 (zero)
#define ESTR  16          // E row stride in shorts
#define L2E   1.4426950408889634f
#define L2E2  2.8853900817779268f

typedef __attribute__((ext_vector_type(8))) short bf16x8;
typedef __attribute__((ext_vector_type(4))) float f32x4;
typedef __attribute__((ext_vector_type(4))) int   i32x4;

#define MFMA(a,b,c) __builtin_amdgcn_mfma_f32_16x16x32_bf16((a),(b),(c),0,0,0)

__device__ inline ushort f2b(float f){
  union { float f; unsigned u; } v; v.f = f;
  unsigned r = v.u + 0x7fff + ((v.u >> 16) & 1);   // RNE to bf16
  return (ushort)(r >> 16);
}
__device__ inline float rcpf(float x){ return __builtin_amdgcn_rcpf(x); }

#if __has_builtin(__builtin_amdgcn_exp2f)
__device__ inline float EXP2(float x){ return __builtin_amdgcn_exp2f(x); }
#else
__device__ inline float EXP2(float x){ return __expf(x * 0.6931471805599453f); }
#endif

// packed f32x2 -> bf16x2 (RNE), 1 instr
__device__ inline unsigned cvt_pk_bf16(float lo, float hi){
  unsigned r;
  asm("v_cvt_pk_bf16_f32 %0, %1, %2" : "=v"(r) : "v"(lo), "v"(hi));
  return r;
}

// ---- prep: bf16 weight repack, pre-scaled by log2(e) for exp2 activations ---
// wcomb[n][k], n<512, k<160: k<128 -> W_hh; k<144 -> W_ih; else 0.
// rows of gate g (n>>7==2) scaled by 2*log2e (tanh), others by log2e (sigmoid).
__global__ void prep_kernel(const float* __restrict__ W_ih, const float* __restrict__ W_hh,
                            const float* __restrict__ W1,   const float* __restrict__ W2,
                            ushort* __restrict__ wcomb, ushort* __restrict__ w1b, ushort* __restrict__ w2b){
  int i = blockIdx.x * blockDim.x + threadIdx.x;
  if (i < 512*KCOMB){
    int n = i / KCOMB, k = i - n*KCOMB;
    float s = ((n >> 7) == 2) ? L2E2 : L2E;
    float v = (k < 128) ? W_hh[n*128 + k]*s : ((k < 144) ? W_ih[n*16 + (k-128)]*s : 0.f);
    wcomb[i] = f2b(v);
  } else if (i < 512*KCOMB + 64*128){
    int j = i - 512*KCOMB;
    w1b[j] = f2b(W1[j] * L2E);
  } else if (i < 512*KCOMB + 64*128 + 32*64){
    int j = i - 512*KCOMB - 64*128;
    w2b[j] = f2b(W2[j] * L2E);
  }
}

// ---- main fused kernel ---------------------------------------------------
// 8 waves forced: each wave owns cols w*16..w*16+15 of ALL 4 gates (cell
// update is lane-local).  launch_bounds(512,4): reg cap 128 (need ~96) ->
// 2 blocks/CU resident (LDS 61.4 KB x2 fits 160 KB) for phase overlap.
__global__ __launch_bounds__(512, 4)
void lstm_kernel(const int* __restrict__ x, const float* __restrict__ emb_table,
                 const float* __restrict__ b_ih, const float* __restrict__ b_hh,
                 const float* __restrict__ b1, const float* __restrict__ b2,
                 const float* __restrict__ W3, const float* __restrict__ b3,
                 const ushort* __restrict__ wcomb, const ushort* __restrict__ w1b,
                 const ushort* __restrict__ w2b, float* __restrict__ out)
{
  __shared__ ushort A_h[2*BROWS*128];                       // 32 KB dbuf h, swizzled
  __shared__ __align__(16) char Ebuf[TSTEP*BROWS*ESTR*2];   // 28.7 KB emb; head aliases

  ushort* E  = (ushort*)Ebuf;
  ushort* y1 = (ushort*)Ebuf;               // [64][64] bf16, swizzled (head reuse)
  float*  y2 = (float*)(Ebuf + 8192);       // [64][33] fp32, padded   (head reuse)

  const int tid  = threadIdx.x;
  const int lane = tid & 63;
  const int w    = tid >> 6;      // wave 0..7
  const int l15  = lane & 15;
  const int lg   = lane >> 4;     // 0..3 (k-group)
  const int r0   = blockIdx.x * BROWS;

  // --- zero init h buffer 0 (16 KB) ---
  { i32x4* az = (i32x4*)A_h;
    #pragma unroll
    for (int i = 0; i < 2; ++i) az[tid + i*512] = (i32x4){0,0,0,0}; }

  // --- stage embeddings (padding_idx=0 -> zeros); halves XOR'd by (r>>2)&1 ---
  for (int idx = tid; idx < BROWS*TSTEP; idx += 512){
    int r = idx / TSTEP, t = idx - r*TSTEP;
    int tok = x[(r0 + r)*TSTEP + t];
    int xr  = (r >> 2) & 1;
    unsigned* dst = (unsigned*)(E + (t*BROWS + r)*ESTR);
    if (tok == 0){
      #pragma unroll
      for (int e = 0; e < 8; ++e) dst[e] = 0u;
    } else {
      const float* src = emb_table + tok*16;
      #pragma unroll
      for (int e = 0; e < 8; ++e)
        dst[((e >> 2) ^ xr)*4 + (e & 3)] = cvt_pk_bf16(src[2*e], src[2*e+1]);
    }
  }

  // --- persistent B fragments: Wcomb[n][k], n = g*128 + w*16 + l15 ---
  bf16x8 bB[4][5];
  #pragma unroll
  for (int g = 0; g < 4; ++g){
    const int n = g*128 + w*16 + l15;
    #pragma unroll
    for (int kt = 0; kt < 5; ++kt)
      bB[g][kt] = *(const bf16x8*)((const short*)wcomb + n*KCOMB + kt*32 + lg*8);
  }

  // --- scaled bias splats (persistent, seed MFMA C) ---
  f32x4 biasv[4];
  #pragma unroll
  for (int g = 0; g < 4; ++g){
    const int n = g*128 + w*16 + l15;
    float bv = (b_ih[n] + b_hh[n]) * ((g == 2) ? L2E2 : L2E);
    biasv[g] = (f32x4){bv,bv,bv,bv};
  }

  // --- cell state fp32: rows (m*16 + lg*4 + r), col w*16+l15 ---
  f32x4 cst[4];
  #pragma unroll
  for (int m = 0; m < 4; ++m) cst[m] = (f32x4){0.f,0.f,0.f,0.f};

  const int j2 = w*16 + l15;

  __syncthreads();   // zero-init + E visible

  // ================= recurrence: 1 barrier/step, dbuf h ==================
  for (int t = 0; t < TSTEP; ++t){
    const ushort* Ar = A_h + (t & 1)*BROWS*128;
    ushort*       Aw = A_h + ((t & 1)^1)*BROWS*128;

    #pragma unroll
    for (int m = 0; m < 4; ++m){
      const int row = m*16 + l15;
      const int swz = (row & 7) << 3;
      const short* base_e = (const short*)Ar + row*128 + ((lg*8) ^ swz);
      const short* base_o = (const short*)Ar + row*128 + ((32 + lg*8) ^ swz);
      bf16x8 aF[5];
      aF[0] = *(const bf16x8*)(base_e);
      aF[1] = *(const bf16x8*)(base_o);
      aF[2] = *(const bf16x8*)(base_e + 64);
      aF[3] = *(const bf16x8*)(base_o + 64);
      // emb k-tile: wcomb rows k=144..159 are zero, so lanes lg>=2 may read
      // any valid half; half-select XOR'd by (row>>2)&1 to spread banks
      aF[4] = *(const bf16x8*)((const short*)E + (t*BROWS + row)*ESTR
                               + (((lg & 1) ^ ((row >> 2) & 1))*8));

      f32x4 acc[4];
      #pragma unroll
      for (int g = 0; g < 4; ++g){
        acc[g] = MFMA(aF[0], bB[g][0], biasv[g]);
        #pragma unroll
        for (int kt = 1; kt < 5; ++kt)
          acc[g] = MFMA(aF[kt], bB[g][kt], acc[g]);
      }

      // --- cell update + h write (exp2-based activations, pre-scaled) ---
      #pragma unroll
      for (int rp = 0; rp < 2; ++rp){
        float h2[2];
        #pragma unroll
        for (int q = 0; q < 2; ++q){
          const int r = rp*2 + q;
          float iv = rcpf(1.f + EXP2(-acc[0][r]));
          float fv = rcpf(1.f + EXP2(-acc[1][r]));
          float gv = __builtin_fmaf(-2.f, rcpf(EXP2(acc[2][r]) + 1.f), 1.f);
          float ov = rcpf(1.f + EXP2(-acc[3][r]));
          float cv = __builtin_fmaf(fv, cst[m][r], iv*gv);
          cst[m][r] = cv;
          h2[q] = ov * __builtin_fmaf(-2.f, rcpf(EXP2(cv*L2E2) + 1.f), 1.f);
        }
        unsigned u = cvt_pk_bf16(h2[0], h2[1]);
        const int row0 = m*16 + lg*4 + rp*2;
        const int row1 = row0 + 1;
        Aw[row0*128 + (j2 ^ ((row0 & 7) << 3))] = (ushort)u;
        Aw[row1*128 + (j2 ^ ((row1 & 7) << 3))] = (ushort)(u >> 16);
      }
    }

    __syncthreads();   // Aw visible; everyone done reading Ar
  }

  // h_last is in buffer 0 (14 toggles)
  const ushort* Hf = A_h;

  // ================= MLP head =================
  // layer 1: [64x128] @ W1^T -> sigmoid -> y1 (bf16, swizzled). mt=w&3, nh=w>>2
  {
    const int mt = w & 3, nh = w >> 2;
    f32x4 acc1[2];
    #pragma unroll
    for (int nt = 0; nt < 2; ++nt){
      float bv = b1[nh*32 + nt*16 + l15] * L2E;
      acc1[nt] = (f32x4){bv,bv,bv,bv};
    }
    const int arow = mt*16 + l15;
    const int aswz = (arow & 7) << 3;
    const short* abase = (const short*)Hf + arow*128;
    #pragma unroll
    for (int kt = 0; kt < 4; ++kt){
      bf16x8 aF = *(const bf16x8*)(abase + ((kt*32 + lg*8) ^ aswz));
      #pragma unroll
      for (int nt = 0; nt < 2; ++nt){
        const int n = nh*32 + nt*16 + l15;
        bf16x8 bF = *(const bf16x8*)((const short*)w1b + n*128 + kt*32 + lg*8);
        acc1[nt] = MFMA(aF, bF, acc1[nt]);
      }
    }
    #pragma unroll
    for (int nt = 0; nt < 2; ++nt)
      #pragma unroll
      for (int r = 0; r < 4; ++r){
        const int row = mt*16 + lg*4 + r;
        const int col = nh*32 + nt*16 + l15;
        y1[row*64 + (col ^ ((row & 7) << 3))] = f2b(rcpf(1.f + EXP2(-acc1[nt][r])));
      }
  }
  __syncthreads();

  // layer 2: [64x64] @ W2^T -> sigmoid -> y2 (fp32, stride 33). waves 0..3
  if (w < 4){
    f32x4 acc2[2];
    #pragma unroll
    for (int nt = 0; nt < 2; ++nt){
      float bv = b2[nt*16 + l15] * L2E;
      acc2[nt] = (f32x4){bv,bv,bv,bv};
    }
    const int arow = w*16 + l15;
    const int aswz = (arow & 7) << 3;
    const short* abase = (const short*)y1 + arow*64;
    #pragma unroll
    for (int kt = 0; kt < 2; ++kt){
      bf16x8 aF = *(const bf16x8*)(abase + ((kt*32 + lg*8) ^ aswz));
      #pragma unroll
      for (int nt = 0; nt < 2; ++nt){
        const int n = nt*16 + l15;
        bf16x8 bF = *(const bf16x8*)((const short*)w2b + n*64 + kt*32 + lg*8);
        acc2[nt] = MFMA(aF, bF, acc2[nt]);
      }
    }
    #pragma unroll
    for (int nt = 0; nt < 2; ++nt)
      #pragma unroll
      for (int r = 0; r < 4; ++r){
        const int row = w*16 + lg*4 + r;
        const int col = nt*16 + l15;
        y2[row*33 + col] = rcpf(1.f + EXP2(-acc2[nt][r]));
      }
  }
  __syncthreads();

  // layer 3: [64x32] @ W3^T[32x2] + b3, fp32 vector (128 threads)
  if (tid < 128){
    const int lr = tid >> 1, oc = tid & 1;
    float s = b3[oc];
    #pragma unroll
    for (int k = 0; k < 32; ++k)
      s += y2[lr*33 + k] * W3[oc*32 + k];
    out[(size_t)(r0 + lr)*2 + oc] = s;
  }
}

extern "C" void kernel_launch(void* const* d_in, const int* in_sizes, int n_in,
                              void* d_out, int out_size, void* d_ws, size_t ws_size,
                              hipStream_t stream){
  const int*   x    = (const int*)  d_in[0];
  const float* emb  = (const float*)d_in[1];
  const float* W_ih = (const float*)d_in[2];
  const float* W_hh = (const float*)d_in[3];
  const float* b_ih = (const float*)d_in[4];
  const float* b_hh = (const float*)d_in[5];
  const float* W1   = (const float*)d_in[6];
  const float* b1   = (const float*)d_in[7];
  const float* W2   = (const float*)d_in[8];
  const float* b2   = (const float*)d_in[9];
  const float* W3   = (const float*)d_in[10];
  const float* b3   = (const float*)d_in[11];
  float* out = (float*)d_out;

  const int B = in_sizes[0] / TSTEP;

  ushort* wcomb = (ushort*)d_ws;
  ushort* w1b   = wcomb + 512*KCOMB;
  ushort* w2b   = w1b + 64*128;

  const int prep_total = 512*KCOMB + 64*128 + 32*64;
  prep_kernel<<<(prep_total + 255)/256, 256, 0, stream>>>(W_ih, W_hh, W1, W2, wcomb, w1b, w2b);
  lstm_kernel<<<B/BROWS, 512, 0, stream>>>(x, emb, b_ih, b_hh, b1, b2, W3, b3,
                                           wcomb, w1b, w2b, out);
}

// Round 6
// 363.742 us; speedup vs baseline: 5.0150x; 5.0150x over previous
//
#include <hip/hip_runtime.h>
#include <hip/hip_bf16.h>

#define TSTEP 14
#define BROWS 128         // two 64-row tiles per block (8 waves)
#define KCOMB 160         // 128 (h) + 16 (emb) + 16 (zero)
#define ESTR  16          // E row stride in shorts
#define L2E   1.4426950408889634f
#define L2E2  2.8853900817779268f

typedef __attribute__((ext_vector_type(8))) short bf16x8;
typedef __attribute__((ext_vector_type(4))) float f32x4;
typedef __attribute__((ext_vector_type(4))) int   i32x4;

#define MFMA(a,b,c) __builtin_amdgcn_mfma_f32_16x16x32_bf16((a),(b),(c),0,0,0)

__device__ inline ushort f2b(float f){
  union { float f; unsigned u; } v; v.f = f;
  unsigned r = v.u + 0x7fff + ((v.u >> 16) & 1);   // RNE to bf16
  return (ushort)(r >> 16);
}
__device__ inline float rcpf(float x){ return __builtin_amdgcn_rcpf(x); }

#if __has_builtin(__builtin_amdgcn_exp2f)
__device__ inline float EXP2(float x){ return __builtin_amdgcn_exp2f(x); }
#else
__device__ inline float EXP2(float x){ return __expf(x * 0.6931471805599453f); }
#endif

// packed f32x2 -> bf16x2 (RNE), 1 instr
__device__ inline unsigned cvt_pk_bf16(float lo, float hi){
  unsigned r;
  asm("v_cvt_pk_bf16_f32 %0, %1, %2" : "=v"(r) : "v"(lo), "v"(hi));
  return r;
}

// ---- prep: bf16 weight repack, pre-scaled by log2(e) for exp2 activations ---
__global__ void prep_kernel(const float* __restrict__ W_ih, const float* __restrict__ W_hh,
                            const float* __restrict__ W1,   const float* __restrict__ W2,
                            ushort* __restrict__ wcomb, ushort* __restrict__ w1b, ushort* __restrict__ w2b){
  int i = blockIdx.x * blockDim.x + threadIdx.x;
  if (i < 512*KCOMB){
    int n = i / KCOMB, k = i - n*KCOMB;
    float s = ((n >> 7) == 2) ? L2E2 : L2E;
    float v = (k < 128) ? W_hh[n*128 + k]*s : ((k < 144) ? W_ih[n*16 + (k-128)]*s : 0.f);
    wcomb[i] = f2b(v);
  } else if (i < 512*KCOMB + 64*128){
    int j = i - 512*KCOMB;
    w1b[j] = f2b(W1[j] * L2E);
  } else if (i < 512*KCOMB + 64*128 + 32*64){
    int j = i - 512*KCOMB - 64*128;
    w2b[j] = f2b(W2[j] * L2E);
  }
}

// ---- main fused kernel ---------------------------------------------------
// 8 waves (forced: 8 x 16 cols x 4 gates = 512 gate-rows; i,f,g,o of a hidden
// unit stay lane-local).  waves_per_eu(2,2): 256-reg budget, no spills
// (round-5 lesson: 4 waves/SIMD needs <=128 regs, impossible with 80-reg bB).
// TWO 64-row batch tiles per block: bB/biasv shared across tiles; independent
// MFMA/activation chains give intra-wave pipe overlap at 1 block/CU.
__global__ __attribute__((amdgpu_flat_work_group_size(512, 512), amdgpu_waves_per_eu(2, 2)))
void lstm_kernel(const int* __restrict__ x, const float* __restrict__ emb_table,
                 const float* __restrict__ b_ih, const float* __restrict__ b_hh,
                 const float* __restrict__ b1, const float* __restrict__ b2,
                 const float* __restrict__ W3, const float* __restrict__ b3,
                 const ushort* __restrict__ wcomb, const ushort* __restrict__ w1b,
                 const ushort* __restrict__ w2b, float* __restrict__ out)
{
  // [tile][buf][64*128] : 64 KB
  __shared__ ushort A_h[2*2*64*128];
  // per tile 14*64*16 shorts = 28 KB; 56 KB total; head bufs alias
  __shared__ __align__(16) char Ebuf[2*TSTEP*64*ESTR*2];

  ushort* E  = (ushort*)Ebuf;
  ushort* y1 = (ushort*)Ebuf;                // [128][64] bf16 swizzled (head reuse)
  float*  y2 = (float*)(Ebuf + 16384);       // [128][33] fp32 padded   (head reuse)

  const int tid  = threadIdx.x;
  const int lane = tid & 63;
  const int w    = tid >> 6;      // wave 0..7
  const int l15  = lane & 15;
  const int lg   = lane >> 4;     // 0..3 (k-group)
  const int r0   = blockIdx.x * BROWS;

  // --- zero init h buffer 0 of both tiles (i32x4 = 8 shorts) ---
  { i32x4* az = (i32x4*)A_h;
    #pragma unroll
    for (int i = 0; i < 2; ++i){
      az[tid + i*512]        = (i32x4){0,0,0,0};   // tile0 buf0
      az[2048 + tid + i*512] = (i32x4){0,0,0,0};   // tile1 buf0
    } }

  // --- stage embeddings (padding_idx=0 -> zeros); halves XOR'd by (rr>>2)&1 ---
  for (int idx = tid; idx < BROWS*TSTEP; idx += 512){
    int r = idx / TSTEP, t = idx - r*TSTEP;
    int tok = x[(r0 + r)*TSTEP + t];
    int tt = r >> 6, rr = r & 63;
    int xr  = (rr >> 2) & 1;
    unsigned* dst = (unsigned*)(E + tt*(TSTEP*64*ESTR) + (t*64 + rr)*ESTR);
    if (tok == 0){
      #pragma unroll
      for (int e = 0; e < 8; ++e) dst[e] = 0u;
    } else {
      const float* src = emb_table + tok*16;
      #pragma unroll
      for (int e = 0; e < 8; ++e)
        dst[((e >> 2) ^ xr)*4 + (e & 3)] = cvt_pk_bf16(src[2*e], src[2*e+1]);
    }
  }

  // --- persistent B fragments: Wcomb[n][k], n = g*128 + w*16 + l15 ---
  bf16x8 bB[4][5];
  #pragma unroll
  for (int g = 0; g < 4; ++g){
    const int n = g*128 + w*16 + l15;
    #pragma unroll
    for (int kt = 0; kt < 5; ++kt)
      bB[g][kt] = *(const bf16x8*)((const short*)wcomb + n*KCOMB + kt*32 + lg*8);
  }

  // --- scaled bias splats (persistent, seed MFMA C) ---
  f32x4 biasv[4];
  #pragma unroll
  for (int g = 0; g < 4; ++g){
    const int n = g*128 + w*16 + l15;
    float bv = (b_ih[n] + b_hh[n]) * ((g == 2) ? L2E2 : L2E);
    biasv[g] = (f32x4){bv,bv,bv,bv};
  }

  // --- cell state fp32: [tile][m], rows (m*16+lg*4+r), col w*16+l15 ---
  f32x4 cst[2][4];
  #pragma unroll
  for (int tt = 0; tt < 2; ++tt)
    #pragma unroll
    for (int m = 0; m < 4; ++m) cst[tt][m] = (f32x4){0.f,0.f,0.f,0.f};

  const int j2 = w*16 + l15;

  __syncthreads();   // zero-init + E visible

  // ================= recurrence: 1 barrier/step, dbuf h, 2 tiles =========
  for (int t = 0; t < TSTEP; ++t){
    const int bufR = t & 1, bufW = bufR ^ 1;

    #pragma unroll
    for (int m = 0; m < 4; ++m){
      #pragma unroll
      for (int tt = 0; tt < 2; ++tt){
        const ushort* Ar = A_h + (tt*2 + bufR)*8192;
        ushort*       Aw = A_h + (tt*2 + bufW)*8192;
        const short*  Et = (const short*)E + tt*(TSTEP*64*ESTR) + t*64*ESTR;

        const int row = m*16 + l15;
        const int swz = (row & 7) << 3;
        const short* base_e = (const short*)Ar + row*128 + ((lg*8) ^ swz);
        const short* base_o = (const short*)Ar + row*128 + ((32 + lg*8) ^ swz);
        bf16x8 aF[5];
        aF[0] = *(const bf16x8*)(base_e);
        aF[1] = *(const bf16x8*)(base_o);
        aF[2] = *(const bf16x8*)(base_e + 64);
        aF[3] = *(const bf16x8*)(base_o + 64);
        // emb k-tile: wcomb rows k=144..159 are zero -> lanes lg>=2 may read
        // any valid half; half-select XOR'd by (row>>2)&1 to spread banks
        aF[4] = *(const bf16x8*)(Et + row*ESTR + (((lg & 1) ^ ((row >> 2) & 1))*8));

        f32x4 acc[4];
        #pragma unroll
        for (int g = 0; g < 4; ++g){
          acc[g] = MFMA(aF[0], bB[g][0], biasv[g]);
          #pragma unroll
          for (int kt = 1; kt < 5; ++kt)
            acc[g] = MFMA(aF[kt], bB[g][kt], acc[g]);
        }

        // --- cell update + h write (exp2-based activations, pre-scaled) ---
        #pragma unroll
        for (int rp = 0; rp < 2; ++rp){
          float h2[2];
          #pragma unroll
          for (int q = 0; q < 2; ++q){
            const int r = rp*2 + q;
            float iv = rcpf(1.f + EXP2(-acc[0][r]));
            float fv = rcpf(1.f + EXP2(-acc[1][r]));
            float gv = __builtin_fmaf(-2.f, rcpf(EXP2(acc[2][r]) + 1.f), 1.f);
            float ov = rcpf(1.f + EXP2(-acc[3][r]));
            float cv = __builtin_fmaf(fv, cst[tt][m][r], iv*gv);
            cst[tt][m][r] = cv;
            h2[q] = ov * __builtin_fmaf(-2.f, rcpf(EXP2(cv*L2E2) + 1.f), 1.f);
          }
          unsigned u = cvt_pk_bf16(h2[0], h2[1]);
          const int row0 = m*16 + lg*4 + rp*2;
          const int row1 = row0 + 1;
          Aw[row0*128 + (j2 ^ ((row0 & 7) << 3))] = (ushort)u;
          Aw[row1*128 + (j2 ^ ((row1 & 7) << 3))] = (ushort)(u >> 16);
        }
      }
    }

    __syncthreads();   // Aw visible; everyone done reading Ar
  }

  // h_last in buf 0 of each tile (14 toggles)

  // ================= MLP head (128 rows) =================
  // layer 1: [128x128] @ W1^T -> sigmoid -> y1 (bf16, swizzled).
  // wave w owns rows w*16..w*16+15, all 64 cols.
  {
    f32x4 acc1[4];
    #pragma unroll
    for (int nt = 0; nt < 4; ++nt){
      float bv = b1[nt*16 + l15] * L2E;
      acc1[nt] = (f32x4){bv,bv,bv,bv};
    }
    const int arowg = w*16 + l15;                 // global row 0..127
    const ushort* Hf = A_h + ((w >> 2)*2 + 0)*8192;
    const int arow = arowg & 63;
    const int aswz = (arow & 7) << 3;
    const short* abase = (const short*)Hf + arow*128;
    #pragma unroll
    for (int kt = 0; kt < 4; ++kt){
      bf16x8 aF = *(const bf16x8*)(abase + ((kt*32 + lg*8) ^ aswz));
      #pragma unroll
      for (int nt = 0; nt < 4; ++nt){
        const int n = nt*16 + l15;
        bf16x8 bF = *(const bf16x8*)((const short*)w1b + n*128 + kt*32 + lg*8);
        acc1[nt] = MFMA(aF, bF, acc1[nt]);
      }
    }
    #pragma unroll
    for (int nt = 0; nt < 4; ++nt)
      #pragma unroll
      for (int r = 0; r < 4; ++r){
        const int row = w*16 + lg*4 + r;          // global row
        const int col = nt*16 + l15;
        y1[row*64 + (col ^ ((row & 7) << 3))] = f2b(rcpf(1.f + EXP2(-acc1[nt][r])));
      }
  }
  __syncthreads();

  // layer 2: [128x64] @ W2^T -> sigmoid -> y2 (fp32, stride 33). all 8 waves
  {
    f32x4 acc2[2];
    #pragma unroll
    for (int nt = 0; nt < 2; ++nt){
      float bv = b2[nt*16 + l15] * L2E;
      acc2[nt] = (f32x4){bv,bv,bv,bv};
    }
    const int arow = w*16 + l15;
    const int aswz = (arow & 7) << 3;
    const short* abase = (const short*)y1 + arow*64;
    #pragma unroll
    for (int kt = 0; kt < 2; ++kt){
      bf16x8 aF = *(const bf16x8*)(abase + ((kt*32 + lg*8) ^ aswz));
      #pragma unroll
      for (int nt = 0; nt < 2; ++nt){
        const int n = nt*16 + l15;
        bf16x8 bF = *(const bf16x8*)((const short*)w2b + n*64 + kt*32 + lg*8);
        acc2[nt] = MFMA(aF, bF, acc2[nt]);
      }
    }
    #pragma unroll
    for (int nt = 0; nt < 2; ++nt)
      #pragma unroll
      for (int r = 0; r < 4; ++r){
        const int row = w*16 + lg*4 + r;
        const int col = nt*16 + l15;
        y2[row*33 + col] = rcpf(1.f + EXP2(-acc2[nt][r]));
      }
  }
  __syncthreads();

  // layer 3: [128x32] @ W3^T[32x2] + b3, fp32 vector (256 threads)
  if (tid < 256){
    const int lr = tid >> 1, oc = tid & 1;
    float s = b3[oc];
    #pragma unroll
    for (int k = 0; k < 32; ++k)
      s += y2[lr*33 + k] * W3[oc*32 + k];
    out[(size_t)(r0 + lr)*2 + oc] = s;
  }
}

extern "C" void kernel_launch(void* const* d_in, const int* in_sizes, int n_in,
                              void* d_out, int out_size, void* d_ws, size_t ws_size,
                              hipStream_t stream){
  const int*   x    = (const int*)  d_in[0];
  const float* emb  = (const float*)d_in[1];
  const float* W_ih = (const float*)d_in[2];
  const float* W_hh = (const float*)d_in[3];
  const float* b_ih = (const float*)d_in[4];
  const float* b_hh = (const float*)d_in[5];
  const float* W1   = (const float*)d_in[6];
  const float* b1   = (const float*)d_in[7];
  const float* W2   = (const float*)d_in[8];
  const float* b2   = (const float*)d_in[9];
  const float* W3   = (const float*)d_in[10];
  const float* b3   = (const float*)d_in[11];
  float* out = (float*)d_out;

  const int B = in_sizes[0] / TSTEP;

  ushort* wcomb = (ushort*)d_ws;
  ushort* w1b   = wcomb + 512*KCOMB;
  ushort* w2b   = w1b + 64*128;

  const int prep_total = 512*KCOMB + 64*128 + 32*64;
  prep_kernel<<<(prep_total + 255)/256, 256, 0, stream>>>(W_ih, W_hh, W1, W2, wcomb, w1b, w2b);
  lstm_kernel<<<B/BROWS, 512, 0, stream>>>(x, emb, b_ih, b_hh, b1, b2, W3, b3,
                                           wcomb, w1b, w2b, out);
}

// Round 7
// 333.889 us; speedup vs baseline: 5.4634x; 1.0894x over previous
//
#include <hip/hip_runtime.h>
#include <hip/hip_bf16.h>

#define TSTEP 14
#define BROWS 128         // two 64-row tiles per block (8 waves)
#define KCOMB 160         // 128 (h) + 16 (emb) + 16 (zero)
#define ESTR  16          // E row stride in shorts
#define L2E   1.4426950408889634f
#define L2E2  2.8853900817779268f

typedef __attribute__((ext_vector_type(8))) short bf16x8;
typedef __attribute__((ext_vector_type(4))) float f32x4;
typedef __attribute__((ext_vector_type(4))) int   i32x4;

// NOTE operand order: A = weight fragment, B = h fragment (swapped vs r6).
#define MFMA(a,b,c) __builtin_amdgcn_mfma_f32_16x16x32_bf16((a),(b),(c),0,0,0)

__device__ inline ushort f2b(float f){
  union { float f; unsigned u; } v; v.f = f;
  unsigned r = v.u + 0x7fff + ((v.u >> 16) & 1);   // RNE to bf16
  return (ushort)(r >> 16);
}
__device__ inline float rcpf(float x){ return __builtin_amdgcn_rcpf(x); }

#if __has_builtin(__builtin_amdgcn_exp2f)
__device__ inline float EXP2(float x){ return __builtin_amdgcn_exp2f(x); }
#else
__device__ inline float EXP2(float x){ return __expf(x * 0.6931471805599453f); }
#endif

// packed f32x2 -> bf16x2 (RNE), 1 instr
__device__ inline unsigned cvt_pk_bf16(float lo, float hi){
  unsigned r;
  asm("v_cvt_pk_bf16_f32 %0, %1, %2" : "=v"(r) : "v"(lo), "v"(hi));
  return r;
}

// ---- prep: bf16 weight repack, pre-scaled by log2(e) for exp2 activations ---
__global__ void prep_kernel(const float* __restrict__ W_ih, const float* __restrict__ W_hh,
                            const float* __restrict__ W1,   const float* __restrict__ W2,
                            ushort* __restrict__ wcomb, ushort* __restrict__ w1b, ushort* __restrict__ w2b){
  int i = blockIdx.x * blockDim.x + threadIdx.x;
  if (i < 512*KCOMB){
    int n = i / KCOMB, k = i - n*KCOMB;
    float s = ((n >> 7) == 2) ? L2E2 : L2E;
    float v = (k < 128) ? W_hh[n*128 + k]*s : ((k < 144) ? W_ih[n*16 + (k-128)]*s : 0.f);
    wcomb[i] = f2b(v);
  } else if (i < 512*KCOMB + 64*128){
    int j = i - 512*KCOMB;
    w1b[j] = f2b(W1[j] * L2E);
  } else if (i < 512*KCOMB + 64*128 + 32*64){
    int j = i - 512*KCOMB - 64*128;
    w2b[j] = f2b(W2[j] * L2E);
  }
}

// --- one gate-GEMM group: 5 ds_reads + 20 MFMA (A=W regs, B=h from LDS) ---
__device__ __forceinline__ void lm_group(const ushort* Ar, const short* Et, int n,
    int l15, int o0, int o1, int o2, int o3, int esel,
    const bf16x8 (&bB)[4][5], const f32x4 (&bias)[4], f32x4 (&acc)[4])
{
  const short* base = (const short*)Ar + n*2048 + l15*128;
  bf16x8 a0 = *(const bf16x8*)(base + o0);
  bf16x8 a1 = *(const bf16x8*)(base + o1);
  bf16x8 a2 = *(const bf16x8*)(base + o2);
  bf16x8 a3 = *(const bf16x8*)(base + o3);
  // emb k-tile: wcomb rows k=144..159 are zero -> lanes lg>=2 read any staged
  // (finite) half; half-select XOR'd by (l15>>2)&1 to spread banks
  bf16x8 a4 = *(const bf16x8*)(Et + n*16*ESTR + l15*ESTR + esel);
  #pragma unroll
  for (int g = 0; g < 4; ++g){
    acc[g] = MFMA(bB[g][0], a0, bias[g]);
    acc[g] = MFMA(bB[g][1], a1, acc[g]);
    acc[g] = MFMA(bB[g][2], a2, acc[g]);
    acc[g] = MFMA(bB[g][3], a3, acc[g]);
    acc[g] = MFMA(bB[g][4], a4, acc[g]);
  }
}

// --- cell update for one group: 7 trans/elem, one ds_write_b64 ---
// lane holds units (w*16+lg*4 .. +3) of batch row (n*16+l15).
__device__ __forceinline__ void act_group(ushort* Aw, int n, int l15, int colswz,
    const f32x4 (&acc)[4], f32x4 &c)
{
  float h2[4];
  #pragma unroll
  for (int r = 0; r < 4; ++r){
    float Aa = EXP2(-acc[0][r]);                 // exp(-i_pre)
    float Ff = EXP2(-acc[1][r]);                 // exp(-f_pre)
    float Bb = EXP2( acc[2][r]);                 // exp(2*g_pre)
    float A1 = 1.f + Aa, F1 = 1.f + Ff, Bp = Bb + 1.f, Bm = Bb - 1.f;
    float P  = A1 * Bp;
    // c' = c*sig(f) + sig(i)*tanh(g) = [c*P + Bm*F1] / (P*F1)
    float cv = __builtin_fmaf(c[r], P, Bm*F1) * rcpf(P*F1);
    c[r] = cv;
    float Oo = EXP2(-acc[3][r]);                 // exp(-o_pre)
    float Ee = EXP2(cv*L2E2);                    // exp(2c)
    // h = sig(o)*tanh(c) = (E-1) / ((1+O)(E+1))
    h2[r] = (Ee - 1.f) * rcpf((1.f + Oo)*(Ee + 1.f));
  }
  unsigned u0 = cvt_pk_bf16(h2[0], h2[1]);
  unsigned u1 = cvt_pk_bf16(h2[2], h2[3]);
  uint2 uu; uu.x = u0; uu.y = u1;
  *(uint2*)(Aw + n*2048 + l15*128 + colswz) = uu;   // 4 units, one b64 write
}

// ---- main fused kernel ---------------------------------------------------
// 8 waves (8 x 16 units x 4 gates = 512 gate-rows; i,f,g,o of a unit stay
// lane-local).  waves_per_eu(2,2): 256-reg budget (r5 lesson: 4 w/SIMD spills).
// Two 64-row tiles; step body is software-pipelined: MFMA(group g+1) issued
// before ACT(group g) so matrix pipe overlaps the trans-pipe activation work.
__global__ __attribute__((amdgpu_flat_work_group_size(512, 512), amdgpu_waves_per_eu(2, 2)))
void lstm_kernel(const int* __restrict__ x, const float* __restrict__ emb_table,
                 const float* __restrict__ b_ih, const float* __restrict__ b_hh,
                 const float* __restrict__ b1, const float* __restrict__ b2,
                 const float* __restrict__ W3, const float* __restrict__ b3,
                 const ushort* __restrict__ wcomb, const ushort* __restrict__ w1b,
                 const ushort* __restrict__ w2b, float* __restrict__ out)
{
  // [tile][buf][64*128] shorts : 64 KB
  __shared__ ushort A_h[2*2*64*128];
  // per tile 14*64*16 shorts = 28 KB; 56 KB total; head bufs alias
  __shared__ __align__(16) char Ebuf[2*TSTEP*64*ESTR*2];

  ushort* E  = (ushort*)Ebuf;
  ushort* y1 = (ushort*)Ebuf;                // [128][64] bf16 swizzled (head reuse)
  float*  y2 = (float*)(Ebuf + 16384);       // [128][33] fp32 padded   (head reuse)

  const int tid  = threadIdx.x;
  const int lane = tid & 63;
  const int w    = tid >> 6;      // wave 0..7
  const int l15  = lane & 15;
  const int lg   = lane >> 4;     // 0..3 (k-group / unit-subgroup)
  const int r0   = blockIdx.x * BROWS;

  // --- zero init h buffer 0 of both tiles ---
  { i32x4* az = (i32x4*)A_h;
    #pragma unroll
    for (int i = 0; i < 2; ++i){
      az[tid + i*512]        = (i32x4){0,0,0,0};   // tile0 buf0
      az[2048 + tid + i*512] = (i32x4){0,0,0,0};   // tile1 buf0
    } }

  // --- stage embeddings (padding_idx=0 -> zeros); t-major, no int division ---
  for (int idx = tid; idx < BROWS*TSTEP; idx += 512){
    int r = idx & 127, t = idx >> 7;
    int tok = x[(r0 + r)*TSTEP + t];
    int tt = r >> 6, rr = r & 63;
    int xr  = (rr >> 2) & 1;
    unsigned* dst = (unsigned*)(E + tt*(TSTEP*64*ESTR) + (t*64 + rr)*ESTR);
    if (tok == 0){
      #pragma unroll
      for (int e = 0; e < 8; ++e) dst[e] = 0u;
    } else {
      const float* src = emb_table + tok*16;
      #pragma unroll
      for (int e = 0; e < 8; ++e)
        dst[((e >> 2) ^ xr)*4 + (e & 3)] = cvt_pk_bf16(src[2*e], src[2*e+1]);
    }
  }

  // --- persistent A fragments (weights): Wcomb[n][k], n = g*128 + w*16 + l15 ---
  bf16x8 bB[4][5];
  #pragma unroll
  for (int g = 0; g < 4; ++g){
    const int n = g*128 + w*16 + l15;
    #pragma unroll
    for (int kt = 0; kt < 5; ++kt)
      bB[g][kt] = *(const bf16x8*)((const short*)wcomb + n*KCOMB + kt*32 + lg*8);
  }

  // --- scaled per-reg biases: acc[g][r] is unit (w*16+lg*4+r) ---
  f32x4 biasv[4];
  #pragma unroll
  for (int g = 0; g < 4; ++g){
    #pragma unroll
    for (int r = 0; r < 4; ++r){
      const int n = g*128 + w*16 + lg*4 + r;
      biasv[g][r] = (b_ih[n] + b_hh[n]) * ((g == 2) ? L2E2 : L2E);
    }
  }

  // --- cell state fp32: [tile][n-tile]; lane: row n*16+l15, units lg*4..+3 ---
  f32x4 cst[2][4];
  #pragma unroll
  for (int tt = 0; tt < 2; ++tt)
    #pragma unroll
    for (int n = 0; n < 4; ++n) cst[tt][n] = (f32x4){0.f,0.f,0.f,0.f};

  // --- static swizzled LDS offsets (t-invariant) ---
  const int sw   = (l15 & 7) << 3;
  const int o0   = (0*32 + lg*8) ^ sw;
  const int o1   = (1*32 + lg*8) ^ sw;
  const int o2   = (2*32 + lg*8) ^ sw;
  const int o3   = (3*32 + lg*8) ^ sw;
  const int esel = ((lg & 1) ^ ((l15 >> 2) & 1)) * 8;
  const int colswz = (w*16 + lg*4) ^ sw;

  __syncthreads();   // zero-init + E visible

  // ================= recurrence: 1 barrier/step, dbuf h, 8-group pipeline ===
  for (int t = 0; t < TSTEP; ++t){
    const int bufR = t & 1, bufW = bufR ^ 1;
    const ushort* Ar0 = A_h + bufR*8192;
    const ushort* Ar1 = A_h + 16384 + bufR*8192;
    ushort*       Aw0 = A_h + bufW*8192;
    ushort*       Aw1 = A_h + 16384 + bufW*8192;
    const short*  Et0 = (const short*)E + t*64*ESTR;
    const short*  Et1 = (const short*)E + TSTEP*64*ESTR + t*64*ESTR;

    f32x4 accA[4], accB[4];
    lm_group(Ar0, Et0, 0, l15, o0,o1,o2,o3, esel, bB, biasv, accA);
    lm_group(Ar0, Et0, 1, l15, o0,o1,o2,o3, esel, bB, biasv, accB);
    act_group(Aw0, 0, l15, colswz, accA, cst[0][0]);
    lm_group(Ar0, Et0, 2, l15, o0,o1,o2,o3, esel, bB, biasv, accA);
    act_group(Aw0, 1, l15, colswz, accB, cst[0][1]);
    lm_group(Ar0, Et0, 3, l15, o0,o1,o2,o3, esel, bB, biasv, accB);
    act_group(Aw0, 2, l15, colswz, accA, cst[0][2]);
    lm_group(Ar1, Et1, 0, l15, o0,o1,o2,o3, esel, bB, biasv, accA);
    act_group(Aw0, 3, l15, colswz, accB, cst[0][3]);
    lm_group(Ar1, Et1, 1, l15, o0,o1,o2,o3, esel, bB, biasv, accB);
    act_group(Aw1, 0, l15, colswz, accA, cst[1][0]);
    lm_group(Ar1, Et1, 2, l15, o0,o1,o2,o3, esel, bB, biasv, accA);
    act_group(Aw1, 1, l15, colswz, accB, cst[1][1]);
    lm_group(Ar1, Et1, 3, l15, o0,o1,o2,o3, esel, bB, biasv, accB);
    act_group(Aw1, 2, l15, colswz, accA, cst[1][2]);
    act_group(Aw1, 3, l15, colswz, accB, cst[1][3]);

    __syncthreads();   // Aw visible; everyone done reading Ar
  }

  // h_last in buf 0 of each tile (14 toggles)

  // ================= MLP head (128 rows) =================
  // layer 1: [128x128] @ W1^T -> sigmoid -> y1 (bf16, swizzled).
  {
    f32x4 acc1[4];
    #pragma unroll
    for (int nt = 0; nt < 4; ++nt){
      float bv = b1[nt*16 + l15] * L2E;
      acc1[nt] = (f32x4){bv,bv,bv,bv};
    }
    const ushort* Hf = A_h + (w >> 2)*16384;     // tile of this wave's rows
    const int arow = (w*16 + l15) & 63;
    const int aswz = (arow & 7) << 3;
    const short* abase = (const short*)Hf + arow*128;
    #pragma unroll
    for (int kt = 0; kt < 4; ++kt){
      bf16x8 aF = *(const bf16x8*)(abase + ((kt*32 + lg*8) ^ aswz));
      #pragma unroll
      for (int nt = 0; nt < 4; ++nt){
        const int n = nt*16 + l15;
        bf16x8 bF = *(const bf16x8*)((const short*)w1b + n*128 + kt*32 + lg*8);
        acc1[nt] = MFMA(aF, bF, acc1[nt]);
      }
    }
    #pragma unroll
    for (int nt = 0; nt < 4; ++nt)
      #pragma unroll
      for (int r = 0; r < 4; ++r){
        const int row = w*16 + lg*4 + r;          // global row
        const int col = nt*16 + l15;
        y1[row*64 + (col ^ ((row & 7) << 3))] = f2b(rcpf(1.f + EXP2(-acc1[nt][r])));
      }
  }
  __syncthreads();

  // layer 2: [128x64] @ W2^T -> sigmoid -> y2 (fp32, stride 33). all 8 waves
  {
    f32x4 acc2[2];
    #pragma unroll
    for (int nt = 0; nt < 2; ++nt){
      float bv = b2[nt*16 + l15] * L2E;
      acc2[nt] = (f32x4){bv,bv,bv,bv};
    }
    const int arow = w*16 + l15;
    const int aswz = (arow & 7) << 3;
    const short* abase = (const short*)y1 + arow*64;
    #pragma unroll
    for (int kt = 0; kt < 2; ++kt){
      bf16x8 aF = *(const bf16x8*)(abase + ((kt*32 + lg*8) ^ aswz));
      #pragma unroll
      for (int nt = 0; nt < 2; ++nt){
        const int n = nt*16 + l15;
        bf16x8 bF = *(const bf16x8*)((const short*)w2b + n*64 + kt*32 + lg*8);
        acc2[nt] = MFMA(aF, bF, acc2[nt]);
      }
    }
    #pragma unroll
    for (int nt = 0; nt < 2; ++nt)
      #pragma unroll
      for (int r = 0; r < 4; ++r){
        const int row = w*16 + lg*4 + r;
        const int col = nt*16 + l15;
        y2[row*33 + col] = rcpf(1.f + EXP2(-acc2[nt][r]));
      }
  }
  __syncthreads();

  // layer 3: [128x32] @ W3^T[32x2] + b3, fp32 vector (256 threads)
  if (tid < 256){
    const int lr = tid >> 1, oc = tid & 1;
    float s = b3[oc];
    #pragma unroll
    for (int k = 0; k < 32; ++k)
      s += y2[lr*33 + k] * W3[oc*32 + k];
    out[(size_t)(r0 + lr)*2 + oc] = s;
  }
}

extern "C" void kernel_launch(void* const* d_in, const int* in_sizes, int n_in,
                              void* d_out, int out_size, void* d_ws, size_t ws_size,
                              hipStream_t stream){
  const int*   x    = (const int*)  d_in[0];
  const float* emb  = (const float*)d_in[1];
  const float* W_ih = (const float*)d_in[2];
  const float* W_hh = (const float*)d_in[3];
  const float* b_ih = (const float*)d_in[4];
  const float* b_hh = (const float*)d_in[5];
  const float* W1   = (const float*)d_in[6];
  const float* b1   = (const float*)d_in[7];
  const float* W2   = (const float*)d_in[8];
  const float* b2   = (const float*)d_in[9];
  const float* W3   = (const float*)d_in[10];
  const float* b3   = (const float*)d_in[11];
  float* out = (float*)d_out;

  const int B = in_sizes[0] / TSTEP;

  ushort* wcomb = (ushort*)d_ws;
  ushort* w1b   = wcomb + 512*KCOMB;
  ushort* w2b   = w1b + 64*128;

  const int prep_total = 512*KCOMB + 64*128 + 32*64;
  prep_kernel<<<(prep_total + 255)/256, 256, 0, stream>>>(W_ih, W_hh, W1, W2, wcomb, w1b, w2b);
  lstm_kernel<<<B/BROWS, 512, 0, stream>>>(x, emb, b_ih, b_hh, b1, b2, W3, b3,
                                           wcomb, w1b, w2b, out);
}